// Round 2
// baseline (321.174 us; speedup 1.0000x reference)
//
#include <hip/hip_runtime.h>
#include <math.h>

#define Q_SCALE (255.0f / 32.0f)
#define PHI 32
#define RHO 64
#define HH 384
#define WW 384
#define BB 8
#define RPB 4              // rows per block
#define QPB (WW / 4)       // 96 pixel-quads per row
#define QSTRIDE (WW + 8)   // LDS row stride (u32) -> 1568 B, 16B-aligned rows

// ---------------------------------------------------------------------------
// Kernel A: build fused lookup table T[v][r], v in 0..7 (quantized levels),
// r in 0..63. The whole per-neighbor MLP collapses to this table because
// floor(x*255/32) for x in [0,1) (plus zero padding) only takes values 0..7
// and everything past the inner ReLU is linear. Mean-over-9 folded in (1/9).
// ---------------------------------------------------------------------------
__global__ __launch_bounds__(512) void build_table_kernel(
    const float* __restrict__ w1, const float* __restrict__ b1,
    const float* __restrict__ w2, const float* __restrict__ b2,
    const float* __restrict__ w3, float* __restrict__ T) {
    __shared__ float h2[8][PHI];
    const int t = threadIdx.x;
    if (t < 256) {
        const int v = t >> 5, c = t & 31;
        float acc = b2[c];
#pragma unroll
        for (int k = 0; k < PHI; ++k) {
            float h1 = fmaxf((float)v * w1[k] + b1[k], 0.0f);
            acc += h1 * w2[k * PHI + c];
        }
        h2[v][c] = acc;
    }
    __syncthreads();
    {
        const int v = t >> 6, r = t & 63;
        float acc = 0.0f;
#pragma unroll
        for (int c = 0; c < PHI; ++c) acc += h2[v][c] * w3[c * RHO + r];
        T[v * RHO + r] = acc * (1.0f / 9.0f);
    }
}

// ---------------------------------------------------------------------------
// Kernel B: block = 4 rows x 96 quads (384 threads) of one image.
// Stage 6 input rows as packed nibble codes 1<<(4q) in LDS; per thread build
// 4 neighbor-histograms from 6 shared column sums; inner loop over 64 output
// channels does 2 uniform LDS b128 table reads + 32 FMAs + 1 dwordx4 store.
// Per channel a block writes 6 KB contiguous (4 full rows).
// ---------------------------------------------------------------------------
__global__ __launch_bounds__(RPB * QPB) void deepset_quad_kernel(
    const float* __restrict__ x, const float* __restrict__ Tg,
    const float* __restrict__ b3, float* __restrict__ out) {
    __shared__ unsigned int qe[RPB + 2][QSTRIDE];  // col w -> index w+1
    __shared__ float Tl[RHO * 8];                  // transposed: Tl[r*8+v]
    __shared__ float b3l[RHO];

    const int tid = threadIdx.x;
    const int blk = blockIdx.x;
    const int b = blk / (HH / RPB);
    const int h0 = (blk % (HH / RPB)) * RPB;

    // stage table (transpose v-major -> r-major) and bias into LDS
    for (int i = tid; i < 8 * RHO; i += RPB * QPB) {
        const int v = i >> 6, r = i & 63;
        Tl[r * 8 + v] = Tg[i];
    }
    if (tid < RHO) b3l[tid] = b3[tid];

    // stage rows h0-1 .. h0+4, quantize, pack as 1 << (4*q); padding -> q=0 -> 1
    const float* xb = x + (size_t)b * HH * WW;
    {
        const int w = tid;  // one column per thread
#pragma unroll
        for (int rr = 0; rr < RPB + 2; ++rr) {
            const int hh = h0 - 1 + rr;
            unsigned int qv = 1u;
            if (hh >= 0 && hh < HH) {
                const float xv = xb[hh * WW + w];
                int q = (int)floorf(xv * Q_SCALE);
                q = q < 0 ? 0 : (q > 7 ? 7 : q);
                qv = 1u << (4 * q);
            }
            qe[rr][w + 1] = qv;
        }
        if (w == 0) {
#pragma unroll
            for (int rr = 0; rr < RPB + 2; ++rr) {
                qe[rr][0] = 1u;
                qe[rr][WW + 1] = 1u;
            }
        }
    }
    __syncthreads();

    const int row = tid / QPB;  // 0..3
    const int qd = tid % QPB;   // 0..95

    // 6 column sums shared by the 4 pixels of the quad (nibble counts <= 3)
    unsigned int cs[6];
#pragma unroll
    for (int j = 0; j < 6; ++j)
        cs[j] = qe[row][4 * qd + j] + qe[row + 1][4 * qd + j] + qe[row + 2][4 * qd + j];

    // 3x3 histograms for the 4 pixels (nibble counts <= 9, no overflow)
    const unsigned int cnt0 = cs[0] + cs[1] + cs[2];
    const unsigned int cnt1 = cs[1] + cs[2] + cs[3];
    const unsigned int cnt2 = cs[2] + cs[3] + cs[4];
    const unsigned int cnt3 = cs[3] + cs[4] + cs[5];

    float c0[8], c1[8], c2[8], c3[8];
#pragma unroll
    for (int v = 0; v < 8; ++v) {
        c0[v] = (float)((cnt0 >> (4 * v)) & 15u);
        c1[v] = (float)((cnt1 >> (4 * v)) & 15u);
        c2[v] = (float)((cnt2 >> (4 * v)) & 15u);
        c3[v] = (float)((cnt3 >> (4 * v)) & 15u);
    }

    // 64 output channels: uniform table reads, 32 FMAs, one dwordx4 store
    float* op = out + ((size_t)b * RHO * HH + (h0 + row)) * WW + 4 * qd;
    const size_t rstride = (size_t)HH * WW;
#pragma unroll 8
    for (int r = 0; r < RHO; ++r) {
        const float4 t0 = *(const float4*)&Tl[r * 8];
        const float4 t1 = *(const float4*)&Tl[r * 8 + 4];
        const float bb = b3l[r];
        float a0 = bb, a1 = bb, a2 = bb, a3 = bb;
        a0 += c0[0] * t0.x + c0[1] * t0.y + c0[2] * t0.z + c0[3] * t0.w;
        a0 += c0[4] * t1.x + c0[5] * t1.y + c0[6] * t1.z + c0[7] * t1.w;
        a1 += c1[0] * t0.x + c1[1] * t0.y + c1[2] * t0.z + c1[3] * t0.w;
        a1 += c1[4] * t1.x + c1[5] * t1.y + c1[6] * t1.z + c1[7] * t1.w;
        a2 += c2[0] * t0.x + c2[1] * t0.y + c2[2] * t0.z + c2[3] * t0.w;
        a2 += c2[4] * t1.x + c2[5] * t1.y + c2[6] * t1.z + c2[7] * t1.w;
        a3 += c3[0] * t0.x + c3[1] * t0.y + c3[2] * t0.z + c3[3] * t0.w;
        a3 += c3[4] * t1.x + c3[5] * t1.y + c3[6] * t1.z + c3[7] * t1.w;
        float4 o;
        o.x = fmaxf(a0, 0.0f);
        o.y = fmaxf(a1, 0.0f);
        o.z = fmaxf(a2, 0.0f);
        o.w = fmaxf(a3, 0.0f);
        *(float4*)op = o;
        op += rstride;
    }
}

extern "C" void kernel_launch(void* const* d_in, const int* in_sizes, int n_in,
                              void* d_out, int out_size, void* d_ws, size_t ws_size,
                              hipStream_t stream) {
    const float* x  = (const float*)d_in[0];
    const float* w1 = (const float*)d_in[1];
    const float* b1 = (const float*)d_in[2];
    const float* w2 = (const float*)d_in[3];
    const float* b2 = (const float*)d_in[4];
    const float* w3 = (const float*)d_in[5];
    const float* b3 = (const float*)d_in[6];
    float* out = (float*)d_out;
    float* T   = (float*)d_ws;  // 8*64 floats = 2 KB

    build_table_kernel<<<1, 512, 0, stream>>>(w1, b1, w2, b2, w3, T);
    deepset_quad_kernel<<<BB * (HH / RPB), RPB * QPB, 0, stream>>>(x, T, b3, out);
}

// Round 3
// 315.368 us; speedup vs baseline: 1.0184x; 1.0184x over previous
//
#include <hip/hip_runtime.h>
#include <math.h>

#define Q_SCALE (255.0f / 32.0f)
#define PHI 32
#define RHO 64
#define HH 384
#define WW 384
#define BB 8
#define RPB 4              // rows per block
#define QPB (WW / 4)       // 96 pixel-quads per row
#define NTHR (RPB * QPB)   // 384 threads
#define QSTRIDE (WW + 8)   // LDS row stride (u32), 16B-aligned rows

typedef float f32x4 __attribute__((ext_vector_type(4)));

// ---------------------------------------------------------------------------
// Single fused kernel. The whole per-neighbor MLP collapses to a [8]x[64]
// table because floor(x*255/32) for x in [0,1) (plus zero padding) only takes
// values 0..7 and everything past the inner ReLU is linear; mean-over-9 is
// folded in as 1/9. Each block (4 rows x 96 quads of one image) rebuilds the
// 2 KB table redundantly (~200 cycles) — cheaper than a separate launch +
// global round-trip.
//
// out[b,r,h,w] = relu(b3[r] + sum_{9 neighbors} T[q_n][r])
// Per thread: 4 consecutive pixels. 3x3 histograms built from 6 shared
// column sums in packed-nibble space (code 1<<(4q), counts <= 9 < 16).
// Inner loop: 64 channels x (2 uniform LDS b128 reads + 32 FMA + 1 nt
// dwordx4 store) -> 8 FMA per output element, the VALU floor for this form.
// ---------------------------------------------------------------------------
__global__ __launch_bounds__(NTHR) void deepset_fused_kernel(
    const float* __restrict__ x,
    const float* __restrict__ w1, const float* __restrict__ b1,
    const float* __restrict__ w2, const float* __restrict__ b2,
    const float* __restrict__ w3, const float* __restrict__ b3,
    float* __restrict__ out) {
    __shared__ float h2[8][PHI];
    __shared__ float Tl[RHO * 8];                  // transposed: Tl[r*8+v]
    __shared__ float b3l[RHO];
    __shared__ unsigned int qe[RPB + 2][QSTRIDE];  // col w -> index w+1

    const int tid = threadIdx.x;
    const int blk = blockIdx.x;
    const int b = blk / (HH / RPB);
    const int h0 = (blk % (HH / RPB)) * RPB;

    // ---- stage rows h0-1 .. h0+4 as packed codes 1<<(4q); padding -> 1 ----
    const float* xb = x + (size_t)b * HH * WW;
    {
        const int w = tid;  // one column per thread
#pragma unroll
        for (int rr = 0; rr < RPB + 2; ++rr) {
            const int hh = h0 - 1 + rr;
            unsigned int qv = 1u;
            if (hh >= 0 && hh < HH) {
                const float xv = xb[hh * WW + w];
                int q = (int)floorf(xv * Q_SCALE);
                q = q < 0 ? 0 : (q > 7 ? 7 : q);
                qv = 1u << (4 * q);
            }
            qe[rr][w + 1] = qv;
        }
        if (w == 0) {
#pragma unroll
            for (int rr = 0; rr < RPB + 2; ++rr) {
                qe[rr][0] = 1u;
                qe[rr][WW + 1] = 1u;
            }
        }
    }

    // ---- table phase 1: h2[v][c] = b2[c] + sum_k relu(v*w1+b1)[k]*w2[k][c]
    if (tid < 256) {
        const int v = tid >> 5, c = tid & 31;
        float acc = b2[c];
#pragma unroll
        for (int k = 0; k < PHI; ++k) {
            float h1 = fmaxf((float)v * w1[k] + b1[k], 0.0f);
            acc += h1 * w2[k * PHI + c];
        }
        h2[v][c] = acc;
    }
    __syncthreads();

    // ---- table phase 2: Tl[r*8+v] = (1/9) * sum_c h2[v][c]*w3[c][r] ----
#pragma unroll
    for (int i = tid; i < 8 * RHO; i += NTHR) {
        const int v = i >> 6, r = i & 63;
        float acc = 0.0f;
#pragma unroll
        for (int c = 0; c < PHI; ++c) acc += h2[v][c] * w3[c * RHO + r];
        Tl[r * 8 + v] = acc * (1.0f / 9.0f);
    }
    if (tid < RHO) b3l[tid] = b3[tid];
    __syncthreads();

    // ---- histograms: 6 column sums shared by the quad's 4 pixels ----
    const int row = tid / QPB;  // 0..3
    const int qd = tid % QPB;   // 0..95
    unsigned int cs[6];
#pragma unroll
    for (int j = 0; j < 6; ++j)
        cs[j] = qe[row][4 * qd + j] + qe[row + 1][4 * qd + j] + qe[row + 2][4 * qd + j];

    const unsigned int cnt0 = cs[0] + cs[1] + cs[2];
    const unsigned int cnt1 = cs[1] + cs[2] + cs[3];
    const unsigned int cnt2 = cs[2] + cs[3] + cs[4];
    const unsigned int cnt3 = cs[3] + cs[4] + cs[5];

    float c0[8], c1[8], c2[8], c3[8];
#pragma unroll
    for (int v = 0; v < 8; ++v) {
        c0[v] = (float)((cnt0 >> (4 * v)) & 15u);
        c1[v] = (float)((cnt1 >> (4 * v)) & 15u);
        c2[v] = (float)((cnt2 >> (4 * v)) & 15u);
        c3[v] = (float)((cnt3 >> (4 * v)) & 15u);
    }

    // ---- 64 channels: uniform table reads, 32 FMA, one nt dwordx4 store ----
    float* op = out + ((size_t)b * RHO * HH + (h0 + row)) * WW + 4 * qd;
    const size_t rstride = (size_t)HH * WW;
#pragma unroll 4
    for (int r = 0; r < RHO; ++r) {
        const float4 t0 = *(const float4*)&Tl[r * 8];
        const float4 t1 = *(const float4*)&Tl[r * 8 + 4];
        const float bb = b3l[r];
        float a0 = bb, a1 = bb, a2 = bb, a3 = bb;
        a0 += c0[0] * t0.x + c0[1] * t0.y + c0[2] * t0.z + c0[3] * t0.w;
        a0 += c0[4] * t1.x + c0[5] * t1.y + c0[6] * t1.z + c0[7] * t1.w;
        a1 += c1[0] * t0.x + c1[1] * t0.y + c1[2] * t0.z + c1[3] * t0.w;
        a1 += c1[4] * t1.x + c1[5] * t1.y + c1[6] * t1.z + c1[7] * t1.w;
        a2 += c2[0] * t0.x + c2[1] * t0.y + c2[2] * t0.z + c2[3] * t0.w;
        a2 += c2[4] * t1.x + c2[5] * t1.y + c2[6] * t1.z + c2[7] * t1.w;
        a3 += c3[0] * t0.x + c3[1] * t0.y + c3[2] * t0.z + c3[3] * t0.w;
        a3 += c3[4] * t1.x + c3[5] * t1.y + c3[6] * t1.z + c3[7] * t1.w;
        f32x4 o;
        o[0] = fmaxf(a0, 0.0f);
        o[1] = fmaxf(a1, 0.0f);
        o[2] = fmaxf(a2, 0.0f);
        o[3] = fmaxf(a3, 0.0f);
        __builtin_nontemporal_store(o, (f32x4*)op);
        op += rstride;
    }
}

extern "C" void kernel_launch(void* const* d_in, const int* in_sizes, int n_in,
                              void* d_out, int out_size, void* d_ws, size_t ws_size,
                              hipStream_t stream) {
    const float* x  = (const float*)d_in[0];
    const float* w1 = (const float*)d_in[1];
    const float* b1 = (const float*)d_in[2];
    const float* w2 = (const float*)d_in[3];
    const float* b2 = (const float*)d_in[4];
    const float* w3 = (const float*)d_in[5];
    const float* b3 = (const float*)d_in[6];
    float* out = (float*)d_out;

    deepset_fused_kernel<<<BB * (HH / RPB), NTHR, 0, stream>>>(
        x, w1, b1, w2, b2, w3, b3, out);
}